// Round 1
// baseline (894.180 us; speedup 1.0000x reference)
//
#include <hip/hip_runtime.h>

#define NN 100000   // nodes (also derived from in_sizes, asserted by construction)
#define CIN 128
#define CH 64
#define CO 40
#define BN_EPS 1e-5f

// ---------- edge dtype detection: int64 vs int32 ----------
__global__ void detect_kernel(const void* edge, int* flag) {
    __shared__ int bad;
    if (threadIdx.x == 0) bad = 0;
    __syncthreads();
    // If edge_index is int64 (values < 2^31), every odd int32 word is 0.
    int v = ((const int*)edge)[2 * threadIdx.x + 1];
    if (v != 0) bad = 1;
    __syncthreads();
    if (threadIdx.x == 0) *flag = bad ? 0 : 1;   // 1 => int64
}

__device__ __forceinline__ int edge_at(const void* edge, int is64, int idx) {
    if (is64) return (int)((const long long*)edge)[idx];
    return ((const int*)edge)[idx];
}

// ---------- init: zero accumulators, deg = 1 (self loop) ----------
__global__ void init_kernel(float* __restrict__ acc1, float* __restrict__ acc2,
                            int* __restrict__ deg, int N) {
    int i = blockIdx.x * 256 + threadIdx.x;
    if (i < N * CH) acc1[i] = 0.0f;
    if (i < N * CO) acc2[i] = 0.0f;
    if (i < N)      deg[i]  = 1;
}

// ---------- degree count over dst ----------
__global__ void deg_kernel(const void* edge, const int* __restrict__ flag,
                           int* __restrict__ deg, int E) {
    int e = blockIdx.x * 256 + threadIdx.x;
    if (e >= E) return;
    int is64 = *flag;
    int d = edge_at(edge, is64, E + e);
    atomicAdd(&deg[d], 1);
}

__global__ void dinv_kernel(const int* __restrict__ deg, float* __restrict__ dinv, int N) {
    int i = blockIdx.x * 256 + threadIdx.x;
    if (i < N) dinv[i] = rsqrtf((float)deg[i]);
}

// ---------- GEMM1: buf1[n,c] = dinv[n] * sum_k x[n,k] * W1[k,c] ----------
__global__ __launch_bounds__(256) void gemm1_kernel(const float* __restrict__ x,
                                                    const float* __restrict__ W1,
                                                    const float* __restrict__ dinv,
                                                    float* __restrict__ buf1, int N) {
    __shared__ float Ws[CIN * CH];      // 32 KB
    __shared__ float xs[4 * CIN];       // 2 KB
    int t = threadIdx.x;
    int nb = blockIdx.x * 4;
    for (int i = t; i < CIN * CH; i += 256) Ws[i] = W1[i];
    for (int i = t; i < 4 * CIN; i += 256) {
        int r = i >> 7;
        int n = nb + r;
        xs[i] = (n < N) ? x[(long long)n * CIN + (i & 127)] : 0.0f;
    }
    __syncthreads();
    int r = t >> 6, c = t & 63;         // one wave per row
    int n = nb + r;
    float acc = 0.0f;
#pragma unroll
    for (int k = 0; k < CIN; ++k) acc += xs[r * CIN + k] * Ws[k * CH + c];
    if (n < N) buf1[(long long)n * CH + c] = acc * dinv[n];
}

// ---------- scatter1: acc1[dst,c] += buf1[src,c] ----------
__global__ __launch_bounds__(256) void scatter1_kernel(const void* edge,
                                                       const int* __restrict__ flag,
                                                       const float* __restrict__ buf1,
                                                       float* __restrict__ acc1, int E) {
    int i = blockIdx.x * 256 + threadIdx.x;
    if (i >= E * CH) return;
    int e = i >> 6, c = i & 63;         // e is wave-uniform -> broadcast idx loads
    int is64 = *flag;
    int s = edge_at(edge, is64, e);
    int d = edge_at(edge, is64, E + e);
    atomicAdd(&acc1[d * CH + c], buf1[s * CH + c]);
}

// ---------- bias + BN + ReLU (layer 1), in place into buf1 ----------
__global__ void bnrelu1_kernel(const float* __restrict__ acc1, float* __restrict__ buf1,
                               const float* __restrict__ dinv,
                               const float* __restrict__ b, const float* __restrict__ g,
                               const float* __restrict__ be, const float* __restrict__ m,
                               const float* __restrict__ v, int N) {
    int i = blockIdx.x * 256 + threadIdx.x;
    if (i >= N * CH) return;
    int n = i >> 6, c = i & 63;
    float z = dinv[n] * (acc1[i] + buf1[i]) + b[c];
    float y = (z - m[c]) * rsqrtf(v[c] + BN_EPS) * g[c] + be[c];
    buf1[i] = fmaxf(y, 0.0f);
}

// ---------- GEMM2: hs2[n,j] = dinv[n] * sum_k buf1[n,k] * W2[k,j] ----------
__global__ __launch_bounds__(256) void gemm2_kernel(const float* __restrict__ x2,
                                                    const float* __restrict__ W2,
                                                    const float* __restrict__ dinv,
                                                    float* __restrict__ hs2, int N) {
    __shared__ float Ws[CH * CO];       // 10 KB
    int t = threadIdx.x;
    for (int i = t; i < CH * CO; i += 256) Ws[i] = W2[i];
    __syncthreads();
    int r = t >> 6, lane = t & 63;      // one wave per row, lanes 0..39 active
    int n = blockIdx.x * 4 + r;
    if (lane >= CO || n >= N) return;
    float acc = 0.0f;
#pragma unroll
    for (int k = 0; k < CH; ++k) acc += x2[(long long)n * CH + k] * Ws[k * CO + lane];
    hs2[(long long)n * CO + lane] = acc * dinv[n];
}

// ---------- scatter2: acc2[dst,j] += hs2[src,j] ----------
__global__ __launch_bounds__(256) void scatter2_kernel(const void* edge,
                                                       const int* __restrict__ flag,
                                                       const float* __restrict__ hs2,
                                                       float* __restrict__ acc2, int E) {
    int i = blockIdx.x * 256 + threadIdx.x;
    if (i >= E * CO) return;
    unsigned ui = (unsigned)i;
    unsigned e = ui / CO;
    unsigned j = ui - e * CO;
    int is64 = *flag;
    int s = edge_at(edge, is64, (int)e);
    int d = edge_at(edge, is64, E + (int)e);
    atomicAdd(&acc2[d * CO + j], hs2[s * CO + j]);
}

// ---------- final: bias + BN + ReLU (layer 2) -> d_out ----------
__global__ void bnrelu2_kernel(const float* __restrict__ acc2, const float* __restrict__ hs2,
                               const float* __restrict__ dinv, float* __restrict__ out,
                               const float* __restrict__ b, const float* __restrict__ g,
                               const float* __restrict__ be, const float* __restrict__ m,
                               const float* __restrict__ v, int N) {
    int i = blockIdx.x * 256 + threadIdx.x;
    if (i >= N * CO) return;
    unsigned ui = (unsigned)i;
    unsigned n = ui / CO;
    unsigned j = ui - n * CO;
    float z = dinv[n] * (acc2[i] + hs2[i]) + b[j];
    float y = (z - m[j]) * rsqrtf(v[j] + BN_EPS) * g[j] + be[j];
    out[i] = fmaxf(y, 0.0f);
}

extern "C" void kernel_launch(void* const* d_in, const int* in_sizes, int n_in,
                              void* d_out, int out_size, void* d_ws, size_t ws_size,
                              hipStream_t stream) {
    const float* x   = (const float*)d_in[0];
    const void*  edge = d_in[1];
    const float* W1  = (const float*)d_in[2];
    const float* b1  = (const float*)d_in[3];
    const float* g1  = (const float*)d_in[4];
    const float* be1 = (const float*)d_in[5];
    const float* m1  = (const float*)d_in[6];
    const float* v1  = (const float*)d_in[7];
    const float* W2  = (const float*)d_in[8];
    const float* b2  = (const float*)d_in[9];
    const float* g2  = (const float*)d_in[10];
    const float* be2 = (const float*)d_in[11];
    const float* m2  = (const float*)d_in[12];
    const float* v2  = (const float*)d_in[13];

    const int N = in_sizes[0] / CIN;        // 100000
    const int E = in_sizes[1] / 2;          // 1600000

    // workspace layout (float units)
    float* ws   = (float*)d_ws;
    int*   deg  = (int*)ws;                 // N
    float* dinv = ws + N;                   // N
    float* buf1 = ws + 2 * N;               // 64N (hs1, then x2 in-place)
    float* acc1 = ws + (2 + CH) * N;        // 64N
    float* hs2  = ws + (2 + 2 * CH) * N;    // 40N
    float* acc2 = ws + (2 + 2 * CH + CO) * N; // 40N
    int*   flag = (int*)(ws + (2 + 2 * CH + 2 * CO) * N);

    float* out = (float*)d_out;

    detect_kernel<<<1, 128, 0, stream>>>(edge, flag);
    init_kernel<<<(N * CH + 255) / 256, 256, 0, stream>>>(acc1, acc2, deg, N);
    deg_kernel<<<(E + 255) / 256, 256, 0, stream>>>(edge, flag, deg, E);
    dinv_kernel<<<(N + 255) / 256, 256, 0, stream>>>(deg, dinv, N);
    gemm1_kernel<<<(N + 3) / 4, 256, 0, stream>>>(x, W1, dinv, buf1, N);
    scatter1_kernel<<<(E * CH + 255) / 256, 256, 0, stream>>>(edge, flag, buf1, acc1, E);
    bnrelu1_kernel<<<(N * CH + 255) / 256, 256, 0, stream>>>(acc1, buf1, dinv, b1, g1, be1, m1, v1, N);
    gemm2_kernel<<<(N + 3) / 4, 256, 0, stream>>>(buf1, W2, dinv, hs2, N);
    scatter2_kernel<<<(E * CO + 255) / 256, 256, 0, stream>>>(edge, flag, hs2, acc2, E);
    bnrelu2_kernel<<<(N * CO + 255) / 256, 256, 0, stream>>>(acc2, hs2, dinv, out, b2, g2, be2, m2, v2, N);
}

// Round 2
// 520.275 us; speedup vs baseline: 1.7187x; 1.7187x over previous
//
#include <hip/hip_runtime.h>

#define CIN 128
#define CH 64
#define CO 40
#define BN_EPS 1e-5f

// ---------- edge dtype detection: int64 vs int32 ----------
__global__ void detect_kernel(const void* edge, int* flag) {
    __shared__ int bad;
    if (threadIdx.x == 0) bad = 0;
    __syncthreads();
    int v = ((const int*)edge)[2 * threadIdx.x + 1];
    if (v != 0) bad = 1;
    __syncthreads();
    if (threadIdx.x == 0) *flag = bad ? 0 : 1;   // 1 => int64
}

__device__ __forceinline__ int edge_at(const void* edge, int is64, int idx) {
    if (is64) return (int)((const long long*)edge)[idx];
    return ((const int*)edge)[idx];
}

// ---------- zero in-degree ----------
__global__ void zero_deg_kernel(int* __restrict__ deg, int N) {
    int i = blockIdx.x * 256 + threadIdx.x;
    if (i < N) deg[i] = 0;
}

// ---------- in-degree count over dst ----------
__global__ void deg_kernel(const void* edge, const int* __restrict__ flag,
                           int* __restrict__ deg, int E) {
    int e = blockIdx.x * 256 + threadIdx.x;
    if (e >= E) return;
    int is64 = *flag;
    int d = edge_at(edge, is64, E + e);
    atomicAdd(&deg[d], 1);
}

__global__ void dinv_kernel(const int* __restrict__ deg, float* __restrict__ dinv, int N) {
    int i = blockIdx.x * 256 + threadIdx.x;
    if (i < N) dinv[i] = rsqrtf((float)(deg[i] + 1));   // +1 self loop
}

// ---------- 3-kernel exclusive scan of indeg -> rowptr, cursor ----------
__global__ void scan1_kernel(const int* __restrict__ indeg, int* __restrict__ bsum, int N) {
    __shared__ int sm[256];
    int t = threadIdx.x;
    int i = blockIdx.x * 256 + t;
    sm[t] = (i < N) ? indeg[i] : 0;
    __syncthreads();
    for (int s = 128; s > 0; s >>= 1) {
        if (t < s) sm[t] += sm[t + s];
        __syncthreads();
    }
    if (t == 0) bsum[blockIdx.x] = sm[0];
}

__global__ void scan2_kernel(int* __restrict__ bsum, int nb) {   // nb <= 512
    __shared__ int sm[512];
    int t = threadIdx.x;
    sm[t] = (t < nb) ? bsum[t] : 0;
    __syncthreads();
    for (int off = 1; off < 512; off <<= 1) {
        int v = (t >= off) ? sm[t - off] : 0;
        __syncthreads();
        sm[t] += v;
        __syncthreads();
    }
    if (t < nb) bsum[t] = (t == 0) ? 0 : sm[t - 1];
}

__global__ void scan3_kernel(const int* __restrict__ indeg, const int* __restrict__ bsum,
                             int* __restrict__ rowptr, int* __restrict__ cursor, int N) {
    __shared__ int sm[256];
    int t = threadIdx.x;
    int i = blockIdx.x * 256 + t;
    int v = (i < N) ? indeg[i] : 0;
    sm[t] = v;
    __syncthreads();
    for (int off = 1; off < 256; off <<= 1) {
        int u = (t >= off) ? sm[t - off] : 0;
        __syncthreads();
        sm[t] += u;
        __syncthreads();
    }
    int excl = sm[t] - v + bsum[blockIdx.x];
    if (i < N) { rowptr[i] = excl; cursor[i] = excl; }
    if (i == N - 1) rowptr[N] = excl + v;   // == E
}

// ---------- CSR build: counting-sort edges by dst ----------
__global__ void csr_kernel(const void* edge, const int* __restrict__ flag,
                           int* __restrict__ cursor, int* __restrict__ csr, int E) {
    int e = blockIdx.x * 256 + threadIdx.x;
    if (e >= E) return;
    int is64 = *flag;
    int s = edge_at(edge, is64, e);
    int d = edge_at(edge, is64, E + e);
    int pos = atomicAdd(&cursor[d], 1);
    csr[pos] = s;
}

// ---------- GEMM1: buf1[n,c] = dinv[n] * sum_k x[n,k] * W1[k,c] ----------
__global__ __launch_bounds__(256) void gemm1_kernel(const float* __restrict__ x,
                                                    const float* __restrict__ W1,
                                                    const float* __restrict__ dinv,
                                                    float* __restrict__ buf1, int N) {
    __shared__ float Ws[CIN * CH];      // 32 KB
    __shared__ float xs[4 * CIN];       // 2 KB
    int t = threadIdx.x;
    int nb = blockIdx.x * 4;
    for (int i = t; i < CIN * CH; i += 256) Ws[i] = W1[i];
    for (int i = t; i < 4 * CIN; i += 256) {
        int r = i >> 7;
        int n = nb + r;
        xs[i] = (n < N) ? x[(long long)n * CIN + (i & 127)] : 0.0f;
    }
    __syncthreads();
    int r = t >> 6, c = t & 63;
    int n = nb + r;
    float acc = 0.0f;
#pragma unroll
    for (int k = 0; k < CIN; ++k) acc += xs[r * CIN + k] * Ws[k * CH + c];
    if (n < N) buf1[(long long)n * CH + c] = acc * dinv[n];
}

// ---------- gather1 + bias + BN + ReLU -> buf2 ----------
__global__ __launch_bounds__(256) void gather1_kernel(const float* __restrict__ buf1,
                                                      const int* __restrict__ rowptr,
                                                      const int* __restrict__ csr,
                                                      const float* __restrict__ dinv,
                                                      const float* __restrict__ b,
                                                      const float* __restrict__ g,
                                                      const float* __restrict__ be,
                                                      const float* __restrict__ m,
                                                      const float* __restrict__ v,
                                                      float* __restrict__ buf2, int N) {
    int t = threadIdx.x;
    int r = t >> 6, c = t & 63;         // one wave per node; lane = channel
    int n = blockIdx.x * 4 + r;
    if (n >= N) return;
    int start = rowptr[n], end = rowptr[n + 1];
    float acc = buf1[n * CH + c];       // self loop
    for (int k = start; k < end; k += 64) {
        int cnt = min(64, end - k);
        int sv = (c < cnt) ? csr[k + c] : 0;   // coalesced idx fetch
        int j = 0;
        for (; j + 1 < cnt; j += 2) {
            int s0 = __shfl(sv, j);
            int s1 = __shfl(sv, j + 1);
            float a0 = buf1[s0 * CH + c];
            float a1 = buf1[s1 * CH + c];
            acc += a0;
            acc += a1;
        }
        if (j < cnt) {
            int s0 = __shfl(sv, j);
            acc += buf1[s0 * CH + c];
        }
    }
    float z = dinv[n] * acc + b[c];
    float y = (z - m[c]) * rsqrtf(v[c] + BN_EPS) * g[c] + be[c];
    buf2[n * CH + c] = fmaxf(y, 0.0f);
}

// ---------- GEMM2: hs2[n,j] = dinv[n] * sum_k buf2[n,k] * W2[k,j] ----------
__global__ __launch_bounds__(256) void gemm2_kernel(const float* __restrict__ x2,
                                                    const float* __restrict__ W2,
                                                    const float* __restrict__ dinv,
                                                    float* __restrict__ hs2, int N) {
    __shared__ float Ws[CH * CO];       // 10 KB
    int t = threadIdx.x;
    for (int i = t; i < CH * CO; i += 256) Ws[i] = W2[i];
    __syncthreads();
    int r = t >> 6, lane = t & 63;
    int n = blockIdx.x * 4 + r;
    if (lane >= CO || n >= N) return;
    float acc = 0.0f;
#pragma unroll
    for (int k = 0; k < CH; ++k) acc += x2[(long long)n * CH + k] * Ws[k * CO + lane];
    hs2[(long long)n * CO + lane] = acc * dinv[n];
}

// ---------- gather2 + bias + BN + ReLU -> out ----------
__global__ __launch_bounds__(256) void gather2_kernel(const float* __restrict__ hs2,
                                                      const int* __restrict__ rowptr,
                                                      const int* __restrict__ csr,
                                                      const float* __restrict__ dinv,
                                                      const float* __restrict__ b,
                                                      const float* __restrict__ g,
                                                      const float* __restrict__ be,
                                                      const float* __restrict__ m,
                                                      const float* __restrict__ v,
                                                      float* __restrict__ out, int N) {
    int t = threadIdx.x;
    int r = t >> 6, c = t & 63;
    int n = blockIdx.x * 4 + r;
    if (n >= N) return;
    int start = rowptr[n], end = rowptr[n + 1];
    float acc = (c < CO) ? hs2[n * CO + c] : 0.0f;   // self loop
    for (int k = start; k < end; k += 64) {
        int cnt = min(64, end - k);
        int sv = (c < cnt) ? csr[k + c] : 0;
        int j = 0;
        for (; j + 1 < cnt; j += 2) {
            int s0 = __shfl(sv, j);
            int s1 = __shfl(sv, j + 1);
            float a0 = (c < CO) ? hs2[s0 * CO + c] : 0.0f;
            float a1 = (c < CO) ? hs2[s1 * CO + c] : 0.0f;
            acc += a0;
            acc += a1;
        }
        if (j < cnt) {
            int s0 = __shfl(sv, j);
            if (c < CO) acc += hs2[s0 * CO + c];
        }
    }
    if (c < CO) {
        float z = dinv[n] * acc + b[c];
        float y = (z - m[c]) * rsqrtf(v[c] + BN_EPS) * g[c] + be[c];
        out[n * CO + c] = fmaxf(y, 0.0f);
    }
}

extern "C" void kernel_launch(void* const* d_in, const int* in_sizes, int n_in,
                              void* d_out, int out_size, void* d_ws, size_t ws_size,
                              hipStream_t stream) {
    const float* x    = (const float*)d_in[0];
    const void*  edge = d_in[1];
    const float* W1  = (const float*)d_in[2];
    const float* b1  = (const float*)d_in[3];
    const float* g1  = (const float*)d_in[4];
    const float* be1 = (const float*)d_in[5];
    const float* m1  = (const float*)d_in[6];
    const float* v1  = (const float*)d_in[7];
    const float* W2  = (const float*)d_in[8];
    const float* b2  = (const float*)d_in[9];
    const float* g2  = (const float*)d_in[10];
    const float* be2 = (const float*)d_in[11];
    const float* m2  = (const float*)d_in[12];
    const float* v2  = (const float*)d_in[13];

    const int N = in_sizes[0] / CIN;        // 100000
    const int E = in_sizes[1] / 2;          // 1600000
    const int nb = (N + 255) / 256;         // 391 (<= 512 by construction)

    // workspace layout (4-byte units)
    float* ws    = (float*)d_ws;
    int*   deg    = (int*)ws;                       // N
    float* dinv   = ws + N;                         // N
    int*   rowptr = (int*)(ws + 2 * N);             // N+1
    int*   cursor = (int*)(ws + 3 * N + 8);         // N
    int*   bsum   = (int*)(ws + 4 * N + 16);        // 512
    int*   csr    = (int*)(ws + 4 * N + 1024);      // E
    float* bigbuf = ws + 4 * N + 1024 + E;
    float* buf1   = bigbuf;                         // 64N
    float* buf2   = bigbuf + (long long)CH * N;     // 64N
    float* hs2    = bigbuf + (long long)2 * CH * N; // 40N
    int*   flag   = (int*)(bigbuf + (long long)(2 * CH + CO) * N);

    float* out = (float*)d_out;

    detect_kernel<<<1, 128, 0, stream>>>(edge, flag);
    zero_deg_kernel<<<nb, 256, 0, stream>>>(deg, N);
    deg_kernel<<<(E + 255) / 256, 256, 0, stream>>>(edge, flag, deg, E);
    dinv_kernel<<<nb, 256, 0, stream>>>(deg, dinv, N);
    scan1_kernel<<<nb, 256, 0, stream>>>(deg, bsum, N);
    scan2_kernel<<<1, 512, 0, stream>>>(bsum, nb);
    scan3_kernel<<<nb, 256, 0, stream>>>(deg, bsum, rowptr, cursor, N);
    csr_kernel<<<(E + 255) / 256, 256, 0, stream>>>(edge, flag, cursor, csr, E);
    gemm1_kernel<<<(N + 3) / 4, 256, 0, stream>>>(x, W1, dinv, buf1, N);
    gather1_kernel<<<(N + 3) / 4, 256, 0, stream>>>(buf1, rowptr, csr, dinv, b1, g1, be1, m1, v1, buf2, N);
    gemm2_kernel<<<(N + 3) / 4, 256, 0, stream>>>(buf2, W2, dinv, hs2, N);
    gather2_kernel<<<(N + 3) / 4, 256, 0, stream>>>(hs2, rowptr, csr, dinv, b2, g2, be2, m2, v2, out, N);
}

// Round 3
// 411.011 us; speedup vs baseline: 2.1756x; 1.2658x over previous
//
#include <hip/hip_runtime.h>

#define CIN 128
#define CH 64
#define CO 40
#define BN_EPS 1e-5f
#define EPB 4096   // edges per pass1 block (16 per thread)

typedef _Float16 h16;

// ---------- edge dtype detection: int64 vs int32 ----------
__global__ void detect_kernel(const void* edge, int* flag) {
    __shared__ int bad;
    if (threadIdx.x == 0) bad = 0;
    __syncthreads();
    int v = ((const int*)edge)[2 * threadIdx.x + 1];
    if (v != 0) bad = 1;
    __syncthreads();
    if (threadIdx.x == 0) *flag = bad ? 0 : 1;   // 1 => int64
}

__device__ __forceinline__ int edge_at(const void* edge, int is64, int idx) {
    if (is64) return (int)((const long long*)edge)[idx];
    return ((const int*)edge)[idx];
}

__global__ void init0_kernel(int* __restrict__ gcnt, int* __restrict__ gcur) {
    gcnt[threadIdx.x] = 0;
    gcur[threadIdx.x] = 0;
}

// ---------- pass1a: per-block LDS histogram of dst buckets ----------
__global__ __launch_bounds__(256) void pass1a_kernel(const void* edge, const int* __restrict__ flag,
                                                     int* __restrict__ gcnt, int E, int NB) {
    __shared__ int hist[512];
    int t = threadIdx.x;
    for (int i = t; i < NB; i += 256) hist[i] = 0;
    __syncthreads();
    int is64 = *flag;
    int base = blockIdx.x * EPB;
#pragma unroll
    for (int i = 0; i < 16; ++i) {
        int e = base + i * 256 + t;
        if (e < E) {
            int d = edge_at(edge, is64, E + e);
            atomicAdd(&hist[d >> 8], 1);
        }
    }
    __syncthreads();
    for (int i = t; i < NB; i += 256) if (hist[i]) atomicAdd(&gcnt[i], hist[i]);
}

// ---------- scanb: exclusive scan of bucket counts (NB <= 512) ----------
__global__ void scanb_kernel(const int* __restrict__ gcnt, int* __restrict__ gbase, int NB) {
    __shared__ int sm[512];
    int t = threadIdx.x;
    int v = (t < NB) ? gcnt[t] : 0;
    sm[t] = v;
    __syncthreads();
    for (int off = 1; off < 512; off <<= 1) {
        int u = (t >= off) ? sm[t - off] : 0;
        __syncthreads();
        sm[t] += u;
        __syncthreads();
    }
    if (t < NB) gbase[t] = sm[t] - v;
}

// ---------- pass1b: stage (src,dst) pairs bucket-contiguously ----------
__global__ __launch_bounds__(256) void pass1b_kernel(const void* edge, const int* __restrict__ flag,
                                                     const int* __restrict__ gbase, int* __restrict__ gcur,
                                                     int2* __restrict__ staging, int E, int NB) {
    __shared__ int hist[512];
    __shared__ int rbase[512];
    int t = threadIdx.x;
    for (int i = t; i < NB; i += 256) hist[i] = 0;
    __syncthreads();
    int is64 = *flag;
    int base = blockIdx.x * EPB;
    int2 ed[16];
#pragma unroll
    for (int i = 0; i < 16; ++i) {
        int e = base + i * 256 + t;
        int2 p; p.x = 0; p.y = -1;
        if (e < E) {
            p.x = edge_at(edge, is64, e);
            p.y = edge_at(edge, is64, E + e);
            atomicAdd(&hist[p.y >> 8], 1);
        }
        ed[i] = p;
    }
    __syncthreads();
    for (int i = t; i < NB; i += 256)
        rbase[i] = hist[i] ? gbase[i] + atomicAdd(&gcur[i], hist[i]) : 0;
    __syncthreads();
    for (int i = t; i < NB; i += 256) hist[i] = 0;   // reuse as local cursor
    __syncthreads();
#pragma unroll
    for (int i = 0; i < 16; ++i) {
        int2 p = ed[i];
        if (p.y >= 0) {
            int b = p.y >> 8;
            int pos = rbase[b] + atomicAdd(&hist[b], 1);
            staging[pos] = p;
        }
    }
}

// ---------- pass2a: per-bucket degree count (coalesced deg write) ----------
__global__ __launch_bounds__(256) void pass2a_kernel(const int2* __restrict__ staging,
                                                     const int* __restrict__ gbase,
                                                     const int* __restrict__ gcnt,
                                                     int* __restrict__ deg, int N) {
    __shared__ int hist[256];
    int b = blockIdx.x, t = threadIdx.x;
    hist[t] = 0;
    __syncthreads();
    int s0 = gbase[b], cnt = gcnt[b];
    for (int i = t; i < cnt; i += 256) {
        int d = staging[s0 + i].y;
        atomicAdd(&hist[d & 255], 1);
    }
    __syncthreads();
    int n = b * 256 + t;
    if (n < N) deg[n] = hist[t];
}

__global__ void dinv_kernel(const int* __restrict__ deg, float* __restrict__ dinv, int N) {
    int i = blockIdx.x * 256 + threadIdx.x;
    if (i < N) dinv[i] = rsqrtf((float)(deg[i] + 1));   // +1 self loop
}

// ---------- 3-kernel exclusive scan of deg -> rowptr ----------
__global__ void scan1_kernel(const int* __restrict__ indeg, int* __restrict__ bsum, int N) {
    __shared__ int sm[256];
    int t = threadIdx.x;
    int i = blockIdx.x * 256 + t;
    sm[t] = (i < N) ? indeg[i] : 0;
    __syncthreads();
    for (int s = 128; s > 0; s >>= 1) {
        if (t < s) sm[t] += sm[t + s];
        __syncthreads();
    }
    if (t == 0) bsum[blockIdx.x] = sm[0];
}

__global__ void scan2_kernel(int* __restrict__ bsum, int nb) {   // nb <= 512
    __shared__ int sm[512];
    int t = threadIdx.x;
    sm[t] = (t < nb) ? bsum[t] : 0;
    __syncthreads();
    for (int off = 1; off < 512; off <<= 1) {
        int v = (t >= off) ? sm[t - off] : 0;
        __syncthreads();
        sm[t] += v;
        __syncthreads();
    }
    if (t < nb) bsum[t] = (t == 0) ? 0 : sm[t - 1];
}

__global__ void scan3_kernel(const int* __restrict__ indeg, const int* __restrict__ bsum,
                             int* __restrict__ rowptr, int N) {
    __shared__ int sm[256];
    int t = threadIdx.x;
    int i = blockIdx.x * 256 + t;
    int v = (i < N) ? indeg[i] : 0;
    sm[t] = v;
    __syncthreads();
    for (int off = 1; off < 256; off <<= 1) {
        int u = (t >= off) ? sm[t - off] : 0;
        __syncthreads();
        sm[t] += u;
        __syncthreads();
    }
    int excl = sm[t] - v + bsum[blockIdx.x];
    if (i < N) rowptr[i] = excl;
    if (i == N - 1) rowptr[N] = excl + v;   // == E
}

// ---------- pass2b: per-bucket scatter into exclusive csr window ----------
__global__ __launch_bounds__(256) void pass2b_kernel(const int2* __restrict__ staging,
                                                     const int* __restrict__ gbase,
                                                     const int* __restrict__ gcnt,
                                                     const int* __restrict__ rowptr,
                                                     int* __restrict__ csr, int N) {
    __shared__ int cur[256];
    int b = blockIdx.x, t = threadIdx.x;
    int n = b * 256 + t;
    cur[t] = (n < N) ? rowptr[n] : 0;
    __syncthreads();
    int s0 = gbase[b], cnt = gcnt[b];
    for (int i = t; i < cnt; i += 256) {
        int2 p = staging[s0 + i];
        int pos = atomicAdd(&cur[p.y & 255], 1);
        csr[pos] = p.x;
    }
}

// ---------- GEMM1: buf1h[n,c] = (h16)(dinv[n] * sum_k x[n,k] * W1[k,c]) ----------
__global__ __launch_bounds__(256) void gemm1_kernel(const float* __restrict__ x,
                                                    const float* __restrict__ W1,
                                                    const float* __restrict__ dinv,
                                                    h16* __restrict__ buf1h, int N) {
    __shared__ float Ws[CIN * CH];      // 32 KB
    __shared__ float xs[4 * CIN];       // 2 KB
    int t = threadIdx.x;
    int nb = blockIdx.x * 4;
    for (int i = t; i < CIN * CH; i += 256) Ws[i] = W1[i];
    for (int i = t; i < 4 * CIN; i += 256) {
        int r = i >> 7;
        int n = nb + r;
        xs[i] = (n < N) ? x[(long long)n * CIN + (i & 127)] : 0.0f;
    }
    __syncthreads();
    int r = t >> 6, c = t & 63;
    int n = nb + r;
    float acc = 0.0f;
#pragma unroll
    for (int k = 0; k < CIN; ++k) acc += xs[r * CIN + k] * Ws[k * CH + c];
    if (n < N) buf1h[(long long)n * CH + c] = (h16)(acc * dinv[n]);
}

// ---------- gather1 + bias + BN + ReLU -> buf2 (fp32) ----------
__global__ __launch_bounds__(256) void gather1_kernel(const h16* __restrict__ buf1h,
                                                      const int* __restrict__ rowptr,
                                                      const int* __restrict__ csr,
                                                      const float* __restrict__ dinv,
                                                      const float* __restrict__ b,
                                                      const float* __restrict__ g,
                                                      const float* __restrict__ be,
                                                      const float* __restrict__ m,
                                                      const float* __restrict__ v,
                                                      float* __restrict__ buf2, int N) {
    int t = threadIdx.x;
    int r = t >> 6, c = t & 63;
    int n = blockIdx.x * 4 + r;
    if (n >= N) return;
    int start = rowptr[n], end = rowptr[n + 1];
    float acc = (float)buf1h[n * CH + c];   // self loop
    for (int k = start; k < end; k += 64) {
        int cnt = min(64, end - k);
        int sv = (c < cnt) ? csr[k + c] : 0;
        int j = 0;
        for (; j + 1 < cnt; j += 2) {
            int s0 = __shfl(sv, j);
            int s1 = __shfl(sv, j + 1);
            float a0 = (float)buf1h[s0 * CH + c];
            float a1 = (float)buf1h[s1 * CH + c];
            acc += a0;
            acc += a1;
        }
        if (j < cnt) {
            int s0 = __shfl(sv, j);
            acc += (float)buf1h[s0 * CH + c];
        }
    }
    float z = dinv[n] * acc + b[c];
    float y = (z - m[c]) * rsqrtf(v[c] + BN_EPS) * g[c] + be[c];
    buf2[n * CH + c] = fmaxf(y, 0.0f);
}

// ---------- GEMM2: hs2h[n,j] = (h16)(dinv[n] * sum_k buf2[n,k] * W2[k,j]) ----------
__global__ __launch_bounds__(256) void gemm2_kernel(const float* __restrict__ x2,
                                                    const float* __restrict__ W2,
                                                    const float* __restrict__ dinv,
                                                    h16* __restrict__ hs2h, int N) {
    __shared__ float Ws[CH * CO];       // 10 KB
    int t = threadIdx.x;
    for (int i = t; i < CH * CO; i += 256) Ws[i] = W2[i];
    __syncthreads();
    int r = t >> 6, lane = t & 63;
    int n = blockIdx.x * 4 + r;
    if (lane >= CO || n >= N) return;
    float acc = 0.0f;
#pragma unroll
    for (int k = 0; k < CH; ++k) acc += x2[(long long)n * CH + k] * Ws[k * CO + lane];
    hs2h[(long long)n * CO + lane] = (h16)(acc * dinv[n]);
}

// ---------- gather2 + bias + BN + ReLU -> out ----------
__global__ __launch_bounds__(256) void gather2_kernel(const h16* __restrict__ hs2h,
                                                      const int* __restrict__ rowptr,
                                                      const int* __restrict__ csr,
                                                      const float* __restrict__ dinv,
                                                      const float* __restrict__ b,
                                                      const float* __restrict__ g,
                                                      const float* __restrict__ be,
                                                      const float* __restrict__ m,
                                                      const float* __restrict__ v,
                                                      float* __restrict__ out, int N) {
    int t = threadIdx.x;
    int r = t >> 6, c = t & 63;
    int n = blockIdx.x * 4 + r;
    if (n >= N) return;
    int start = rowptr[n], end = rowptr[n + 1];
    float acc = (c < CO) ? (float)hs2h[n * CO + c] : 0.0f;   // self loop
    for (int k = start; k < end; k += 64) {
        int cnt = min(64, end - k);
        int sv = (c < cnt) ? csr[k + c] : 0;
        int j = 0;
        for (; j + 1 < cnt; j += 2) {
            int s0 = __shfl(sv, j);
            int s1 = __shfl(sv, j + 1);
            float a0 = (c < CO) ? (float)hs2h[s0 * CO + c] : 0.0f;
            float a1 = (c < CO) ? (float)hs2h[s1 * CO + c] : 0.0f;
            acc += a0;
            acc += a1;
        }
        if (j < cnt) {
            int s0 = __shfl(sv, j);
            if (c < CO) acc += (float)hs2h[s0 * CO + c];
        }
    }
    if (c < CO) {
        float z = dinv[n] * acc + b[c];
        float y = (z - m[c]) * rsqrtf(v[c] + BN_EPS) * g[c] + be[c];
        out[n * CO + c] = fmaxf(y, 0.0f);
    }
}

extern "C" void kernel_launch(void* const* d_in, const int* in_sizes, int n_in,
                              void* d_out, int out_size, void* d_ws, size_t ws_size,
                              hipStream_t stream) {
    const float* x    = (const float*)d_in[0];
    const void*  edge = d_in[1];
    const float* W1  = (const float*)d_in[2];
    const float* b1  = (const float*)d_in[3];
    const float* g1  = (const float*)d_in[4];
    const float* be1 = (const float*)d_in[5];
    const float* m1  = (const float*)d_in[6];
    const float* v1  = (const float*)d_in[7];
    const float* W2  = (const float*)d_in[8];
    const float* b2  = (const float*)d_in[9];
    const float* g2  = (const float*)d_in[10];
    const float* be2 = (const float*)d_in[11];
    const float* m2  = (const float*)d_in[12];
    const float* v2  = (const float*)d_in[13];

    const int N  = in_sizes[0] / CIN;       // 100000
    const int E  = in_sizes[1] / 2;         // 1600000
    const int nb = (N + 255) / 256;         // 391  (buckets AND scan blocks)
    const int NB = nb;                      // buckets (<= 512 for N <= 131072)
    const int nblk1 = (E + EPB - 1) / EPB;  // pass1 blocks

    // workspace layout (4-byte units; keep staging 8B-aligned)
    float* ws     = (float*)d_ws;
    size_t off = 0;
    int*   deg    = (int*)(ws + off);           off += N;
    float* dinv   = ws + off;                   off += N;
    int*   rowptr = (int*)(ws + off);           off += N + 2;
    int*   bsum   = (int*)(ws + off);           off += 512;
    int*   gcnt   = (int*)(ws + off);           off += 512;
    int*   gbase  = (int*)(ws + off);           off += 512;
    int*   gcur   = (int*)(ws + off);           off += 512;
    off = (off + 1) & ~(size_t)1;               // 8B align
    int2*  staging = (int2*)(ws + off);         off += (size_t)2 * E;
    int*   csr    = (int*)(ws + off);           off += E;
    h16*   buf1h  = (h16*)(ws + off);           off += (size_t)(CH / 2) * N + 2;
    float* buf2   = ws + off;                   off += (size_t)CH * N;
    h16*   hs2h   = (h16*)(ws + off);           off += (size_t)(CO / 2) * N + 2;
    int*   flag   = (int*)(ws + off);

    float* out = (float*)d_out;

    detect_kernel<<<1, 128, 0, stream>>>(edge, flag);
    init0_kernel<<<1, 512, 0, stream>>>(gcnt, gcur);
    pass1a_kernel<<<nblk1, 256, 0, stream>>>(edge, flag, gcnt, E, NB);
    scanb_kernel<<<1, 512, 0, stream>>>(gcnt, gbase, NB);
    pass1b_kernel<<<nblk1, 256, 0, stream>>>(edge, flag, gbase, gcur, staging, E, NB);
    pass2a_kernel<<<NB, 256, 0, stream>>>(staging, gbase, gcnt, deg, N);
    dinv_kernel<<<nb, 256, 0, stream>>>(deg, dinv, N);
    scan1_kernel<<<nb, 256, 0, stream>>>(deg, bsum, N);
    scan2_kernel<<<1, 512, 0, stream>>>(bsum, nb);
    scan3_kernel<<<nb, 256, 0, stream>>>(deg, bsum, rowptr, N);
    pass2b_kernel<<<NB, 256, 0, stream>>>(staging, gbase, gcnt, rowptr, csr, N);
    gemm1_kernel<<<(N + 3) / 4, 256, 0, stream>>>(x, W1, dinv, buf1h, N);
    gather1_kernel<<<(N + 3) / 4, 256, 0, stream>>>(buf1h, rowptr, csr, dinv, b1, g1, be1, m1, v1, buf2, N);
    gemm2_kernel<<<(N + 3) / 4, 256, 0, stream>>>(buf2, W2, dinv, hs2h, N);
    gather2_kernel<<<(N + 3) / 4, 256, 0, stream>>>(hs2h, rowptr, csr, dinv, b2, g2, be2, m2, v2, out, N);
}

// Round 4
// 277.431 us; speedup vs baseline: 3.2231x; 1.4815x over previous
//
#include <hip/hip_runtime.h>

#define CIN 128
#define CH 64
#define CO 40
#define BN_EPS 1e-5f
#define EPB 4096   // edges per pass1 block (16 per thread)

typedef _Float16 h16;
typedef _Float16 f16x8 __attribute__((ext_vector_type(8)));
typedef float f32x4 __attribute__((ext_vector_type(4)));

// ---------- edge dtype detection: int64 vs int32 ----------
__global__ void detect_kernel(const void* edge, int* flag) {
    __shared__ int bad;
    if (threadIdx.x == 0) bad = 0;
    __syncthreads();
    int v = ((const int*)edge)[2 * threadIdx.x + 1];
    if (v != 0) bad = 1;
    __syncthreads();
    if (threadIdx.x == 0) *flag = bad ? 0 : 1;   // 1 => int64
}

__device__ __forceinline__ int edge_at(const void* edge, int is64, int idx) {
    if (is64) return (int)((const long long*)edge)[idx];
    return ((const int*)edge)[idx];
}

__global__ void init0_kernel(int* __restrict__ gcnt, int* __restrict__ gcur) {
    gcnt[threadIdx.x] = 0;
    gcur[threadIdx.x] = 0;
}

// ---------- W prep: transpose + fp16 convert ----------
// W1t[c][k] (64x128), W2t[c][k] (48x64, cols 40..47 zero)
__global__ void wprep_kernel(const float* __restrict__ W1, const float* __restrict__ W2,
                             h16* __restrict__ W1t, h16* __restrict__ W2t) {
    int t = threadIdx.x;
    for (int i = t; i < 64 * 128; i += 256) {
        int c = i >> 7, k = i & 127;
        W1t[i] = (h16)W1[k * CH + c];
    }
    for (int i = t; i < 48 * 64; i += 256) {
        int c = i >> 6, k = i & 63;
        W2t[i] = (h16)((c < CO) ? W2[k * CO + c] : 0.0f);
    }
}

// ---------- pass1a: per-block LDS histogram of dst buckets ----------
__global__ __launch_bounds__(256) void pass1a_kernel(const void* edge, const int* __restrict__ flag,
                                                     int* __restrict__ gcnt, int E, int NB) {
    __shared__ int hist[512];
    int t = threadIdx.x;
    for (int i = t; i < NB; i += 256) hist[i] = 0;
    __syncthreads();
    int is64 = *flag;
    int base = blockIdx.x * EPB;
#pragma unroll
    for (int i = 0; i < 16; ++i) {
        int e = base + i * 256 + t;
        if (e < E) {
            int d = edge_at(edge, is64, E + e);
            atomicAdd(&hist[d >> 8], 1);
        }
    }
    __syncthreads();
    for (int i = t; i < NB; i += 256) if (hist[i]) atomicAdd(&gcnt[i], hist[i]);
}

// ---------- scanb: exclusive scan of bucket counts (NB <= 512) ----------
__global__ void scanb_kernel(const int* __restrict__ gcnt, int* __restrict__ gbase, int NB) {
    __shared__ int sm[512];
    int t = threadIdx.x;
    int v = (t < NB) ? gcnt[t] : 0;
    sm[t] = v;
    __syncthreads();
    for (int off = 1; off < 512; off <<= 1) {
        int u = (t >= off) ? sm[t - off] : 0;
        __syncthreads();
        sm[t] += u;
        __syncthreads();
    }
    if (t < NB) gbase[t] = sm[t] - v;
}

// ---------- pass1b: stage (src,dst) pairs bucket-contiguously ----------
__global__ __launch_bounds__(256) void pass1b_kernel(const void* edge, const int* __restrict__ flag,
                                                     const int* __restrict__ gbase, int* __restrict__ gcur,
                                                     int2* __restrict__ staging, int E, int NB) {
    __shared__ int hist[512];
    __shared__ int rbase[512];
    int t = threadIdx.x;
    for (int i = t; i < NB; i += 256) hist[i] = 0;
    __syncthreads();
    int is64 = *flag;
    int base = blockIdx.x * EPB;
    int2 ed[16];
#pragma unroll
    for (int i = 0; i < 16; ++i) {
        int e = base + i * 256 + t;
        int2 p; p.x = 0; p.y = -1;
        if (e < E) {
            p.x = edge_at(edge, is64, e);
            p.y = edge_at(edge, is64, E + e);
            atomicAdd(&hist[p.y >> 8], 1);
        }
        ed[i] = p;
    }
    __syncthreads();
    for (int i = t; i < NB; i += 256)
        rbase[i] = hist[i] ? gbase[i] + atomicAdd(&gcur[i], hist[i]) : 0;
    __syncthreads();
    for (int i = t; i < NB; i += 256) hist[i] = 0;   // reuse as local cursor
    __syncthreads();
#pragma unroll
    for (int i = 0; i < 16; ++i) {
        int2 p = ed[i];
        if (p.y >= 0) {
            int b = p.y >> 8;
            int pos = rbase[b] + atomicAdd(&hist[b], 1);
            staging[pos] = p;
        }
    }
}

// ---------- pass2a: per-bucket degree count (coalesced deg write) ----------
__global__ __launch_bounds__(256) void pass2a_kernel(const int2* __restrict__ staging,
                                                     const int* __restrict__ gbase,
                                                     const int* __restrict__ gcnt,
                                                     int* __restrict__ deg, int N) {
    __shared__ int hist[256];
    int b = blockIdx.x, t = threadIdx.x;
    hist[t] = 0;
    __syncthreads();
    int s0 = gbase[b], cnt = gcnt[b];
    for (int i = t; i < cnt; i += 256) {
        int d = staging[s0 + i].y;
        atomicAdd(&hist[d & 255], 1);
    }
    __syncthreads();
    int n = b * 256 + t;
    if (n < N) deg[n] = hist[t];
}

__global__ void dinv_kernel(const int* __restrict__ deg, float* __restrict__ dinv, int N) {
    int i = blockIdx.x * 256 + threadIdx.x;
    if (i < N) dinv[i] = rsqrtf((float)(deg[i] + 1));   // +1 self loop
}

// ---------- 3-kernel exclusive scan of deg -> rowptr ----------
__global__ void scan1_kernel(const int* __restrict__ indeg, int* __restrict__ bsum, int N) {
    __shared__ int sm[256];
    int t = threadIdx.x;
    int i = blockIdx.x * 256 + t;
    sm[t] = (i < N) ? indeg[i] : 0;
    __syncthreads();
    for (int s = 128; s > 0; s >>= 1) {
        if (t < s) sm[t] += sm[t + s];
        __syncthreads();
    }
    if (t == 0) bsum[blockIdx.x] = sm[0];
}

__global__ void scan2_kernel(int* __restrict__ bsum, int nb) {   // nb <= 512
    __shared__ int sm[512];
    int t = threadIdx.x;
    sm[t] = (t < nb) ? bsum[t] : 0;
    __syncthreads();
    for (int off = 1; off < 512; off <<= 1) {
        int v = (t >= off) ? sm[t - off] : 0;
        __syncthreads();
        sm[t] += v;
        __syncthreads();
    }
    if (t < nb) bsum[t] = (t == 0) ? 0 : sm[t - 1];
}

__global__ void scan3_kernel(const int* __restrict__ indeg, const int* __restrict__ bsum,
                             int* __restrict__ rowptr, int N) {
    __shared__ int sm[256];
    int t = threadIdx.x;
    int i = blockIdx.x * 256 + t;
    int v = (i < N) ? indeg[i] : 0;
    sm[t] = v;
    __syncthreads();
    for (int off = 1; off < 256; off <<= 1) {
        int u = (t >= off) ? sm[t - off] : 0;
        __syncthreads();
        sm[t] += u;
        __syncthreads();
    }
    int excl = sm[t] - v + bsum[blockIdx.x];
    if (i < N) rowptr[i] = excl;
    if (i == N - 1) rowptr[N] = excl + v;   // == E
}

// ---------- pass2b: per-bucket scatter into exclusive csr window ----------
__global__ __launch_bounds__(256) void pass2b_kernel(const int2* __restrict__ staging,
                                                     const int* __restrict__ gbase,
                                                     const int* __restrict__ gcnt,
                                                     const int* __restrict__ rowptr,
                                                     int* __restrict__ csr, int N) {
    __shared__ int cur[256];
    int b = blockIdx.x, t = threadIdx.x;
    int n = b * 256 + t;
    cur[t] = (n < N) ? rowptr[n] : 0;
    __syncthreads();
    int s0 = gbase[b], cnt = gcnt[b];
    for (int i = t; i < cnt; i += 256) {
        int2 p = staging[s0 + i];
        int pos = atomicAdd(&cur[p.y & 255], 1);
        csr[pos] = p.x;
    }
}

// ---------- GEMM1 (MFMA f16): buf1h[n,c] = (h16)(dinv[n] * sum_k x[n,k] * W1[k,c]) ----------
// block: 64 rows x 64 cols; 4 waves = 4 row-tiles of 16; K=128 in 4 steps of 32.
__global__ __launch_bounds__(256) void gemm1_kernel(const float* __restrict__ x,
                                                    const h16* __restrict__ W1t,
                                                    const float* __restrict__ dinv,
                                                    h16* __restrict__ buf1h, int N) {
    __shared__ h16 Ws[64 * 128];        // 16 KB, XOR-swizzled
    int t = threadIdx.x;
    // stage W1t [c][k] -> LDS, swizzle byte ^= (c&7)<<4
    for (int i = t; i < 64 * 16; i += 256) {
        int c = i >> 4, kc = (i & 15) * 8;
        unsigned byte = (unsigned)(c * 256 + kc * 2) ^ ((unsigned)(c & 7) << 4);
        *(f16x8*)&Ws[byte >> 1] = *(const f16x8*)&W1t[c * 128 + kc];
    }
    __syncthreads();
    int w = t >> 6, l = t & 63;
    int lm = l & 15, lk = l >> 4;
    int n0 = blockIdx.x * 64 + w * 16;
    const float* xrow = x + (long long)min(n0 + lm, N - 1) * CIN;
    f32x4 acc[4] = {};
#pragma unroll
    for (int ks = 0; ks < 4; ++ks) {
        int k0 = ks * 32 + lk * 8;
        float4 xa = *(const float4*)(xrow + k0);
        float4 xb = *(const float4*)(xrow + k0 + 4);
        f16x8 a;
        a[0] = (h16)xa.x; a[1] = (h16)xa.y; a[2] = (h16)xa.z; a[3] = (h16)xa.w;
        a[4] = (h16)xb.x; a[5] = (h16)xb.y; a[6] = (h16)xb.z; a[7] = (h16)xb.w;
#pragma unroll
        for (int ct = 0; ct < 4; ++ct) {
            int c = ct * 16 + lm;
            unsigned byte = (unsigned)(c * 256 + k0 * 2) ^ ((unsigned)(lm & 7) << 4);
            f16x8 b = *(const f16x8*)&Ws[byte >> 1];
            acc[ct] = __builtin_amdgcn_mfma_f32_16x16x32_f16(a, b, acc[ct], 0, 0, 0);
        }
    }
    // C/D: col = ct*16+lm, row = lk*4 + r
#pragma unroll
    for (int r = 0; r < 4; ++r) {
        int n = n0 + lk * 4 + r;
        if (n < N) {
            float dv = dinv[n];
#pragma unroll
            for (int ct = 0; ct < 4; ++ct)
                buf1h[n * CH + ct * 16 + lm] = (h16)(acc[ct][r] * dv);
        }
    }
}

// ---------- gather1 + bias + BN + ReLU -> buf2 (f16) ----------
__global__ __launch_bounds__(256) void gather1_kernel(const h16* __restrict__ buf1h,
                                                      const int* __restrict__ rowptr,
                                                      const int* __restrict__ csr,
                                                      const float* __restrict__ dinv,
                                                      const float* __restrict__ b,
                                                      const float* __restrict__ g,
                                                      const float* __restrict__ be,
                                                      const float* __restrict__ m,
                                                      const float* __restrict__ v,
                                                      h16* __restrict__ buf2, int N) {
    int t = threadIdx.x;
    int r = t >> 6, c = t & 63;
    int n = blockIdx.x * 4 + r;
    if (n >= N) return;
    int start = rowptr[n], end = rowptr[n + 1];
    float acc = (float)buf1h[n * CH + c];   // self loop
    for (int k = start; k < end; k += 64) {
        int cnt = min(64, end - k);
        int sv = (c < cnt) ? csr[k + c] : 0;
        int j = 0;
        for (; j + 1 < cnt; j += 2) {
            int s0 = __shfl(sv, j);
            int s1 = __shfl(sv, j + 1);
            float a0 = (float)buf1h[s0 * CH + c];
            float a1 = (float)buf1h[s1 * CH + c];
            acc += a0;
            acc += a1;
        }
        if (j < cnt) {
            int s0 = __shfl(sv, j);
            acc += (float)buf1h[s0 * CH + c];
        }
    }
    float z = dinv[n] * acc + b[c];
    float y = (z - m[c]) * rsqrtf(v[c] + BN_EPS) * g[c] + be[c];
    buf2[n * CH + c] = (h16)fmaxf(y, 0.0f);
}

// ---------- GEMM2 (MFMA f16): hs2h[n,j] = (h16)(dinv[n] * sum_k buf2[n,k] * W2[k,j]) ----------
// block: 64 rows x 48 cols (cols 40..47 masked); K=64 in 2 steps.
__global__ __launch_bounds__(256) void gemm2_kernel(const h16* __restrict__ x2,
                                                    const h16* __restrict__ W2t,
                                                    const float* __restrict__ dinv,
                                                    h16* __restrict__ hs2h, int N) {
    __shared__ h16 Ws[48 * 64];         // 6 KB, XOR-swizzled
    int t = threadIdx.x;
    for (int i = t; i < 48 * 8; i += 256) {
        int c = i >> 3, kc = (i & 7) * 8;
        unsigned byte = (unsigned)(c * 128 + kc * 2) ^ ((unsigned)(c & 7) << 4);
        *(f16x8*)&Ws[byte >> 1] = *(const f16x8*)&W2t[c * 64 + kc];
    }
    __syncthreads();
    int w = t >> 6, l = t & 63;
    int lm = l & 15, lk = l >> 4;
    int n0 = blockIdx.x * 64 + w * 16;
    const h16* xrow = x2 + (long long)min(n0 + lm, N - 1) * CH;
    f32x4 acc[3] = {};
#pragma unroll
    for (int ks = 0; ks < 2; ++ks) {
        int k0 = ks * 32 + lk * 8;
        f16x8 a = *(const f16x8*)(xrow + k0);
#pragma unroll
        for (int ct = 0; ct < 3; ++ct) {
            int c = ct * 16 + lm;
            unsigned byte = (unsigned)(c * 128 + k0 * 2) ^ ((unsigned)(lm & 7) << 4);
            f16x8 b = *(const f16x8*)&Ws[byte >> 1];
            acc[ct] = __builtin_amdgcn_mfma_f32_16x16x32_f16(a, b, acc[ct], 0, 0, 0);
        }
    }
#pragma unroll
    for (int r = 0; r < 4; ++r) {
        int n = n0 + lk * 4 + r;
        if (n < N) {
            float dv = dinv[n];
#pragma unroll
            for (int ct = 0; ct < 3; ++ct) {
                int c = ct * 16 + lm;
                if (c < CO) hs2h[n * CO + c] = (h16)(acc[ct][r] * dv);
            }
        }
    }
}

// ---------- gather2 + bias + BN + ReLU -> out ----------
__global__ __launch_bounds__(256) void gather2_kernel(const h16* __restrict__ hs2h,
                                                      const int* __restrict__ rowptr,
                                                      const int* __restrict__ csr,
                                                      const float* __restrict__ dinv,
                                                      const float* __restrict__ b,
                                                      const float* __restrict__ g,
                                                      const float* __restrict__ be,
                                                      const float* __restrict__ m,
                                                      const float* __restrict__ v,
                                                      float* __restrict__ out, int N) {
    int t = threadIdx.x;
    int r = t >> 6, c = t & 63;
    int n = blockIdx.x * 4 + r;
    if (n >= N) return;
    int start = rowptr[n], end = rowptr[n + 1];
    float acc = (c < CO) ? (float)hs2h[n * CO + c] : 0.0f;   // self loop
    for (int k = start; k < end; k += 64) {
        int cnt = min(64, end - k);
        int sv = (c < cnt) ? csr[k + c] : 0;
        int j = 0;
        for (; j + 1 < cnt; j += 2) {
            int s0 = __shfl(sv, j);
            int s1 = __shfl(sv, j + 1);
            float a0 = (c < CO) ? (float)hs2h[s0 * CO + c] : 0.0f;
            float a1 = (c < CO) ? (float)hs2h[s1 * CO + c] : 0.0f;
            acc += a0;
            acc += a1;
        }
        if (j < cnt) {
            int s0 = __shfl(sv, j);
            if (c < CO) acc += (float)hs2h[s0 * CO + c];
        }
    }
    if (c < CO) {
        float z = dinv[n] * acc + b[c];
        float y = (z - m[c]) * rsqrtf(v[c] + BN_EPS) * g[c] + be[c];
        out[n * CO + c] = fmaxf(y, 0.0f);
    }
}

extern "C" void kernel_launch(void* const* d_in, const int* in_sizes, int n_in,
                              void* d_out, int out_size, void* d_ws, size_t ws_size,
                              hipStream_t stream) {
    const float* x    = (const float*)d_in[0];
    const void*  edge = d_in[1];
    const float* W1  = (const float*)d_in[2];
    const float* b1  = (const float*)d_in[3];
    const float* g1  = (const float*)d_in[4];
    const float* be1 = (const float*)d_in[5];
    const float* m1  = (const float*)d_in[6];
    const float* v1  = (const float*)d_in[7];
    const float* W2  = (const float*)d_in[8];
    const float* b2  = (const float*)d_in[9];
    const float* g2  = (const float*)d_in[10];
    const float* be2 = (const float*)d_in[11];
    const float* m2  = (const float*)d_in[12];
    const float* v2  = (const float*)d_in[13];

    const int N  = in_sizes[0] / CIN;       // 100000
    const int E  = in_sizes[1] / 2;         // 1600000
    const int nb = (N + 255) / 256;         // 391
    const int NB = nb;
    const int nblk1 = (E + EPB - 1) / EPB;
    const int nb64 = (N + 63) / 64;         // 1563

    // workspace layout (4-byte units; staging 8B-aligned)
    float* ws     = (float*)d_ws;
    size_t off = 0;
    int*   deg    = (int*)(ws + off);           off += N;
    float* dinv   = ws + off;                   off += N;
    int*   rowptr = (int*)(ws + off);           off += N + 2;
    int*   bsum   = (int*)(ws + off);           off += 512;
    int*   gcnt   = (int*)(ws + off);           off += 512;
    int*   gbase  = (int*)(ws + off);           off += 512;
    int*   gcur   = (int*)(ws + off);           off += 512;
    off = (off + 1) & ~(size_t)1;               // 8B align
    int2*  staging = (int2*)(ws + off);         off += (size_t)2 * E;
    int*   csr    = (int*)(ws + off);           off += E;
    h16*   W1t    = (h16*)(ws + off);           off += 64 * 128 / 2;
    h16*   W2t    = (h16*)(ws + off);           off += 48 * 64 / 2;
    h16*   buf1h  = (h16*)(ws + off);           off += (size_t)(CH / 2) * N + 4;
    h16*   buf2   = (h16*)(ws + off);           off += (size_t)(CH / 2) * N + 4;
    h16*   hs2h   = (h16*)(ws + off);           off += (size_t)(CO / 2) * N + 4;
    int*   flag   = (int*)(ws + off);

    float* out = (float*)d_out;

    detect_kernel<<<1, 128, 0, stream>>>(edge, flag);
    init0_kernel<<<1, 512, 0, stream>>>(gcnt, gcur);
    wprep_kernel<<<1, 256, 0, stream>>>(W1, W2, W1t, W2t);
    pass1a_kernel<<<nblk1, 256, 0, stream>>>(edge, flag, gcnt, E, NB);
    scanb_kernel<<<1, 512, 0, stream>>>(gcnt, gbase, NB);
    pass1b_kernel<<<nblk1, 256, 0, stream>>>(edge, flag, gbase, gcur, staging, E, NB);
    pass2a_kernel<<<NB, 256, 0, stream>>>(staging, gbase, gcnt, deg, N);
    dinv_kernel<<<nb, 256, 0, stream>>>(deg, dinv, N);
    scan1_kernel<<<nb, 256, 0, stream>>>(deg, bsum, N);
    scan2_kernel<<<1, 512, 0, stream>>>(bsum, nb);
    scan3_kernel<<<nb, 256, 0, stream>>>(deg, bsum, rowptr, N);
    pass2b_kernel<<<NB, 256, 0, stream>>>(staging, gbase, gcnt, rowptr, csr, N);
    gemm1_kernel<<<nb64, 256, 0, stream>>>(x, W1t, dinv, buf1h, N);
    gather1_kernel<<<(N + 3) / 4, 256, 0, stream>>>(buf1h, rowptr, csr, dinv, b1, g1, be1, m1, v1, buf2, N);
    gemm2_kernel<<<nb64, 256, 0, stream>>>(buf2, W2t, dinv, hs2h, N);
    gather2_kernel<<<(N + 3) / 4, 256, 0, stream>>>(hs2h, rowptr, csr, dinv, b2, g2, be2, m2, v2, out, N);
}

// Round 5
// 254.927 us; speedup vs baseline: 3.5076x; 1.0883x over previous
//
#include <hip/hip_runtime.h>

#define CIN 128
#define CH 64
#define CO 40
#define BN_EPS 1e-5f
#define EPB 4096   // edges per pass1 block (16 per thread)

typedef _Float16 h16;
typedef _Float16 f16x8 __attribute__((ext_vector_type(8)));
typedef float f32x4 __attribute__((ext_vector_type(4)));

// ---------- edge dtype detection: int64 vs int32 ----------
__global__ void detect_kernel(const void* edge, int* flag) {
    __shared__ int bad;
    if (threadIdx.x == 0) bad = 0;
    __syncthreads();
    int v = ((const int*)edge)[2 * threadIdx.x + 1];
    if (v != 0) bad = 1;
    __syncthreads();
    if (threadIdx.x == 0) *flag = bad ? 0 : 1;   // 1 => int64
}

__device__ __forceinline__ int edge_at(const void* edge, int is64, int idx) {
    if (is64) return (int)((const long long*)edge)[idx];
    return ((const int*)edge)[idx];
}

__global__ void init0_kernel(int* __restrict__ gcnt, int* __restrict__ gcur) {
    gcnt[threadIdx.x] = 0;
    gcur[threadIdx.x] = 0;
}

// ---------- W prep: transpose + fp16 convert ----------
__global__ void wprep_kernel(const float* __restrict__ W1, const float* __restrict__ W2,
                             h16* __restrict__ W1t, h16* __restrict__ W2t) {
    int t = threadIdx.x;
    for (int i = t; i < 64 * 128; i += 256) {
        int c = i >> 7, k = i & 127;
        W1t[i] = (h16)W1[k * CH + c];
    }
    for (int i = t; i < 48 * 64; i += 256) {
        int c = i >> 6, k = i & 63;
        W2t[i] = (h16)((c < CO) ? W2[k * CO + c] : 0.0f);
    }
}

// ---------- pass1a: per-block LDS histogram of dst buckets ----------
__global__ __launch_bounds__(256) void pass1a_kernel(const void* edge, const int* __restrict__ flag,
                                                     int* __restrict__ gcnt, int E, int NB) {
    __shared__ int hist[512];
    int t = threadIdx.x;
    for (int i = t; i < NB; i += 256) hist[i] = 0;
    __syncthreads();
    int is64 = *flag;
    int base = blockIdx.x * EPB;
#pragma unroll
    for (int i = 0; i < 16; ++i) {
        int e = base + i * 256 + t;
        if (e < E) {
            int d = edge_at(edge, is64, E + e);
            atomicAdd(&hist[d >> 8], 1);
        }
    }
    __syncthreads();
    for (int i = t; i < NB; i += 256) if (hist[i]) atomicAdd(&gcnt[i], hist[i]);
}

// ---------- scanb: exclusive scan of bucket counts (NB <= 512) ----------
__global__ void scanb_kernel(const int* __restrict__ gcnt, int* __restrict__ gbase, int NB) {
    __shared__ int sm[512];
    int t = threadIdx.x;
    int v = (t < NB) ? gcnt[t] : 0;
    sm[t] = v;
    __syncthreads();
    for (int off = 1; off < 512; off <<= 1) {
        int u = (t >= off) ? sm[t - off] : 0;
        __syncthreads();
        sm[t] += u;
        __syncthreads();
    }
    if (t < NB) gbase[t] = sm[t] - v;
}

// ---------- pass1b: stage (src,dst) pairs bucket-contiguously ----------
__global__ __launch_bounds__(256) void pass1b_kernel(const void* edge, const int* __restrict__ flag,
                                                     const int* __restrict__ gbase, int* __restrict__ gcur,
                                                     int2* __restrict__ staging, int E, int NB) {
    __shared__ int hist[512];
    __shared__ int rbase[512];
    int t = threadIdx.x;
    for (int i = t; i < NB; i += 256) hist[i] = 0;
    __syncthreads();
    int is64 = *flag;
    int base = blockIdx.x * EPB;
    int2 ed[16];
#pragma unroll
    for (int i = 0; i < 16; ++i) {
        int e = base + i * 256 + t;
        int2 p; p.x = 0; p.y = -1;
        if (e < E) {
            p.x = edge_at(edge, is64, e);
            p.y = edge_at(edge, is64, E + e);
            atomicAdd(&hist[p.y >> 8], 1);
        }
        ed[i] = p;
    }
    __syncthreads();
    for (int i = t; i < NB; i += 256)
        rbase[i] = hist[i] ? gbase[i] + atomicAdd(&gcur[i], hist[i]) : 0;
    __syncthreads();
    for (int i = t; i < NB; i += 256) hist[i] = 0;   // reuse as local cursor
    __syncthreads();
#pragma unroll
    for (int i = 0; i < 16; ++i) {
        int2 p = ed[i];
        if (p.y >= 0) {
            int b = p.y >> 8;
            int pos = rbase[b] + atomicAdd(&hist[b], 1);
            staging[pos] = p;
        }
    }
}

// ---------- pass2f: per bucket — deg hist, local scan -> rowptr+dinv, csr scatter ----------
// rowptr[n] = gbase[b] + local exclusive scan; bucket contiguity makes this globally consistent.
__global__ __launch_bounds__(256) void pass2f_kernel(const int2* __restrict__ staging,
                                                     const int* __restrict__ gbase,
                                                     const int* __restrict__ gcnt,
                                                     int* __restrict__ rowptr,
                                                     float* __restrict__ dinv,
                                                     int* __restrict__ csr, int N) {
    __shared__ int hist[256];
    __shared__ int scan[256];
    __shared__ int cur[256];
    int b = blockIdx.x, t = threadIdx.x;
    hist[t] = 0;
    __syncthreads();
    int s0 = gbase[b], cnt = gcnt[b];
    for (int i = t; i < cnt; i += 256) {
        int d = staging[s0 + i].y;
        atomicAdd(&hist[d & 255], 1);
    }
    __syncthreads();
    int v = hist[t];
    scan[t] = v;
    __syncthreads();
    for (int off = 1; off < 256; off <<= 1) {
        int u = (t >= off) ? scan[t - off] : 0;
        __syncthreads();
        scan[t] += u;
        __syncthreads();
    }
    int ex = scan[t] - v;               // exclusive
    cur[t] = ex;
    int n = b * 256 + t;
    if (n <= N) rowptr[n] = s0 + ex;    // n==N lands here in the last bucket -> E
    if (n < N)  dinv[n]   = rsqrtf((float)(v + 1));   // +1 self loop
    __syncthreads();
    for (int i = t; i < cnt; i += 256) {
        int2 p = staging[s0 + i];
        int pos = atomicAdd(&cur[p.y & 255], 1);
        csr[s0 + pos] = p.x;
    }
}

// ---------- GEMM1 (MFMA f16) ----------
__global__ __launch_bounds__(256) void gemm1_kernel(const float* __restrict__ x,
                                                    const h16* __restrict__ W1t,
                                                    const float* __restrict__ dinv,
                                                    h16* __restrict__ buf1h, int N) {
    __shared__ h16 Ws[64 * 128];        // 16 KB, XOR-swizzled
    int t = threadIdx.x;
    for (int i = t; i < 64 * 16; i += 256) {
        int c = i >> 4, kc = (i & 15) * 8;
        unsigned byte = (unsigned)(c * 256 + kc * 2) ^ ((unsigned)(c & 7) << 4);
        *(f16x8*)&Ws[byte >> 1] = *(const f16x8*)&W1t[c * 128 + kc];
    }
    __syncthreads();
    int w = t >> 6, l = t & 63;
    int lm = l & 15, lk = l >> 4;
    int n0 = blockIdx.x * 64 + w * 16;
    const float* xrow = x + (long long)min(n0 + lm, N - 1) * CIN;
    f32x4 acc[4] = {};
#pragma unroll
    for (int ks = 0; ks < 4; ++ks) {
        int k0 = ks * 32 + lk * 8;
        float4 xa = *(const float4*)(xrow + k0);
        float4 xb = *(const float4*)(xrow + k0 + 4);
        f16x8 a;
        a[0] = (h16)xa.x; a[1] = (h16)xa.y; a[2] = (h16)xa.z; a[3] = (h16)xa.w;
        a[4] = (h16)xb.x; a[5] = (h16)xb.y; a[6] = (h16)xb.z; a[7] = (h16)xb.w;
#pragma unroll
        for (int ct = 0; ct < 4; ++ct) {
            int c = ct * 16 + lm;
            unsigned byte = (unsigned)(c * 256 + k0 * 2) ^ ((unsigned)(lm & 7) << 4);
            f16x8 b = *(const f16x8*)&Ws[byte >> 1];
            acc[ct] = __builtin_amdgcn_mfma_f32_16x16x32_f16(a, b, acc[ct], 0, 0, 0);
        }
    }
#pragma unroll
    for (int r = 0; r < 4; ++r) {
        int n = n0 + lk * 4 + r;
        if (n < N) {
            float dv = dinv[n];
#pragma unroll
            for (int ct = 0; ct < 4; ++ct)
                buf1h[n * CH + ct * 16 + lm] = (h16)(acc[ct][r] * dv);
        }
    }
}

// ---------- gather1 + bias + BN + ReLU -> buf2 (f16), unroll-8 ----------
__global__ __launch_bounds__(256) void gather1_kernel(const h16* __restrict__ buf1h,
                                                      const int* __restrict__ rowptr,
                                                      const int* __restrict__ csr,
                                                      const float* __restrict__ dinv,
                                                      const float* __restrict__ b,
                                                      const float* __restrict__ g,
                                                      const float* __restrict__ be,
                                                      const float* __restrict__ m,
                                                      const float* __restrict__ v,
                                                      h16* __restrict__ buf2, int N) {
    int t = threadIdx.x;
    int r = t >> 6, c = t & 63;
    int n = blockIdx.x * 4 + r;
    if (n >= N) return;
    int start = rowptr[n], end = rowptr[n + 1];
    float acc = (float)buf1h[n * CH + c];   // self loop
    for (int k = start; k < end; k += 64) {
        int cnt = min(64, end - k);
        int sv = (c < cnt) ? csr[k + c] : 0;
        int j = 0;
        for (; j + 8 <= cnt; j += 8) {
            int s[8];
#pragma unroll
            for (int u = 0; u < 8; ++u) s[u] = __shfl(sv, j + u);
            float a[8];
#pragma unroll
            for (int u = 0; u < 8; ++u) a[u] = (float)buf1h[s[u] * CH + c];
#pragma unroll
            for (int u = 0; u < 8; ++u) acc += a[u];
        }
        for (; j < cnt; ++j) {
            int s0 = __shfl(sv, j);
            acc += (float)buf1h[s0 * CH + c];
        }
    }
    float z = dinv[n] * acc + b[c];
    float y = (z - m[c]) * rsqrtf(v[c] + BN_EPS) * g[c] + be[c];
    buf2[n * CH + c] = (h16)fmaxf(y, 0.0f);
}

// ---------- GEMM2 (MFMA f16) ----------
__global__ __launch_bounds__(256) void gemm2_kernel(const h16* __restrict__ x2,
                                                    const h16* __restrict__ W2t,
                                                    const float* __restrict__ dinv,
                                                    h16* __restrict__ hs2h, int N) {
    __shared__ h16 Ws[48 * 64];         // 6 KB, XOR-swizzled
    int t = threadIdx.x;
    for (int i = t; i < 48 * 8; i += 256) {
        int c = i >> 3, kc = (i & 7) * 8;
        unsigned byte = (unsigned)(c * 128 + kc * 2) ^ ((unsigned)(c & 7) << 4);
        *(f16x8*)&Ws[byte >> 1] = *(const f16x8*)&W2t[c * 64 + kc];
    }
    __syncthreads();
    int w = t >> 6, l = t & 63;
    int lm = l & 15, lk = l >> 4;
    int n0 = blockIdx.x * 64 + w * 16;
    const h16* xrow = x2 + (long long)min(n0 + lm, N - 1) * CH;
    f32x4 acc[3] = {};
#pragma unroll
    for (int ks = 0; ks < 2; ++ks) {
        int k0 = ks * 32 + lk * 8;
        f16x8 a = *(const f16x8*)(xrow + k0);
#pragma unroll
        for (int ct = 0; ct < 3; ++ct) {
            int c = ct * 16 + lm;
            unsigned byte = (unsigned)(c * 128 + k0 * 2) ^ ((unsigned)(lm & 7) << 4);
            f16x8 b = *(const f16x8*)&Ws[byte >> 1];
            acc[ct] = __builtin_amdgcn_mfma_f32_16x16x32_f16(a, b, acc[ct], 0, 0, 0);
        }
    }
#pragma unroll
    for (int r = 0; r < 4; ++r) {
        int n = n0 + lk * 4 + r;
        if (n < N) {
            float dv = dinv[n];
#pragma unroll
            for (int ct = 0; ct < 3; ++ct) {
                int c = ct * 16 + lm;
                if (c < CO) hs2h[n * CO + c] = (h16)(acc[ct][r] * dv);
            }
        }
    }
}

// ---------- gather2 + bias + BN + ReLU -> out, unroll-8 ----------
__global__ __launch_bounds__(256) void gather2_kernel(const h16* __restrict__ hs2h,
                                                      const int* __restrict__ rowptr,
                                                      const int* __restrict__ csr,
                                                      const float* __restrict__ dinv,
                                                      const float* __restrict__ b,
                                                      const float* __restrict__ g,
                                                      const float* __restrict__ be,
                                                      const float* __restrict__ m,
                                                      const float* __restrict__ v,
                                                      float* __restrict__ out, int N) {
    int t = threadIdx.x;
    int r = t >> 6, c = t & 63;
    int n = blockIdx.x * 4 + r;
    if (n >= N) return;
    int start = rowptr[n], end = rowptr[n + 1];
    float acc = (c < CO) ? (float)hs2h[n * CO + c] : 0.0f;   // self loop
    for (int k = start; k < end; k += 64) {
        int cnt = min(64, end - k);
        int sv = (c < cnt) ? csr[k + c] : 0;
        int j = 0;
        for (; j + 8 <= cnt; j += 8) {
            int s[8];
#pragma unroll
            for (int u = 0; u < 8; ++u) s[u] = __shfl(sv, j + u);
            float a[8];
#pragma unroll
            for (int u = 0; u < 8; ++u) a[u] = (c < CO) ? (float)hs2h[s[u] * CO + c] : 0.0f;
#pragma unroll
            for (int u = 0; u < 8; ++u) acc += a[u];
        }
        for (; j < cnt; ++j) {
            int s0 = __shfl(sv, j);
            if (c < CO) acc += (float)hs2h[s0 * CO + c];
        }
    }
    if (c < CO) {
        float z = dinv[n] * acc + b[c];
        float y = (z - m[c]) * rsqrtf(v[c] + BN_EPS) * g[c] + be[c];
        out[n * CO + c] = fmaxf(y, 0.0f);
    }
}

extern "C" void kernel_launch(void* const* d_in, const int* in_sizes, int n_in,
                              void* d_out, int out_size, void* d_ws, size_t ws_size,
                              hipStream_t stream) {
    const float* x    = (const float*)d_in[0];
    const void*  edge = d_in[1];
    const float* W1  = (const float*)d_in[2];
    const float* b1  = (const float*)d_in[3];
    const float* g1  = (const float*)d_in[4];
    const float* be1 = (const float*)d_in[5];
    const float* m1  = (const float*)d_in[6];
    const float* v1  = (const float*)d_in[7];
    const float* W2  = (const float*)d_in[8];
    const float* b2  = (const float*)d_in[9];
    const float* g2  = (const float*)d_in[10];
    const float* be2 = (const float*)d_in[11];
    const float* m2  = (const float*)d_in[12];
    const float* v2  = (const float*)d_in[13];

    const int N  = in_sizes[0] / CIN;       // 100000
    const int E  = in_sizes[1] / 2;         // 1600000
    const int NB = (N + 255) / 256;         // 391 buckets
    const int nblk1 = (E + EPB - 1) / EPB;
    const int nb64 = (N + 63) / 64;

    // workspace layout (4-byte units; staging 8B-aligned)
    float* ws     = (float*)d_ws;
    size_t off = 0;
    float* dinv   = ws + off;                   off += N;
    int*   rowptr = (int*)(ws + off);           off += N + 2;
    int*   gcnt   = (int*)(ws + off);           off += 512;
    int*   gbase  = (int*)(ws + off);           off += 512;
    int*   gcur   = (int*)(ws + off);           off += 512;
    off = (off + 1) & ~(size_t)1;               // 8B align
    int2*  staging = (int2*)(ws + off);         off += (size_t)2 * E;
    int*   csr    = (int*)(ws + off);           off += E;
    h16*   W1t    = (h16*)(ws + off);           off += 64 * 128 / 2;
    h16*   W2t    = (h16*)(ws + off);           off += 48 * 64 / 2;
    h16*   buf1h  = (h16*)(ws + off);           off += (size_t)(CH / 2) * N + 4;
    h16*   buf2   = (h16*)(ws + off);           off += (size_t)(CH / 2) * N + 4;
    h16*   hs2h   = (h16*)(ws + off);           off += (size_t)(CO / 2) * N + 4;
    int*   flag   = (int*)(ws + off);

    float* out = (float*)d_out;

    detect_kernel<<<1, 128, 0, stream>>>(edge, flag);
    init0_kernel<<<1, 512, 0, stream>>>(gcnt, gcur);
    wprep_kernel<<<1, 256, 0, stream>>>(W1, W2, W1t, W2t);
    pass1a_kernel<<<nblk1, 256, 0, stream>>>(edge, flag, gcnt, E, NB);
    scanb_kernel<<<1, 512, 0, stream>>>(gcnt, gbase, NB);
    pass1b_kernel<<<nblk1, 256, 0, stream>>>(edge, flag, gbase, gcur, staging, E, NB);
    pass2f_kernel<<<NB, 256, 0, stream>>>(staging, gbase, gcnt, rowptr, dinv, csr, N);
    gemm1_kernel<<<nb64, 256, 0, stream>>>(x, W1t, dinv, buf1h, N);
    gather1_kernel<<<(N + 3) / 4, 256, 0, stream>>>(buf1h, rowptr, csr, dinv, b1, g1, be1, m1, v1, buf2, N);
    gemm2_kernel<<<nb64, 256, 0, stream>>>(buf2, W2t, dinv, hs2h, N);
    gather2_kernel<<<(N + 3) / 4, 256, 0, stream>>>(hs2h, rowptr, csr, dinv, b2, g2, be2, m2, v2, out, N);
}